// Round 5
// baseline (83.527 us; speedup 1.0000x reference)
//
#include <hip/hip_runtime.h>

#define NJ 24
#define EPSF 1e-6f

__global__ __launch_bounds__(256) void shCaster_kernel(
    const float* __restrict__ xyz,          // [N,3] fp32
    const float* __restrict__ vdirs,        // [N,3] fp32
    const float* __restrict__ transforms,   // [NJ,4,4] fp32
    const float* __restrict__ sh_feats,     // [NJ,9] fp32
    const float* __restrict__ locs,         // [NJ,3] fp32
    float* __restrict__ out,                // fp32: [3N xyz_out][3N vd_out]
    int N)
{
    constexpr float SH_C0 = 0.28209479177387814f;
    constexpr float SH_C1 = 0.4886025119029199f;
    constexpr float C2_0 = 1.0925484305920792f;
    constexpr float C2_1 = -1.0925484305920792f;
    constexpr float C2_2 = 0.31539156525252005f;
    constexpr float C2_3 = -1.0925484305920792f;
    constexpr float C2_4 = 0.5462742152960396f;

    // Stage joint constants in LDS (rows 0..2 of each 4x4 only).
    __shared__ float sT[NJ * 12];   // [j][row(0..2)][col(0..3)]
    __shared__ float sF[NJ * 9];
    __shared__ float sL[NJ * 3];

    const int tid = threadIdx.x;
    for (int i = tid; i < NJ * 16; i += 256) {
        int j = i >> 4, rc = i & 15, r = rc >> 2, c = rc & 3;
        if (r < 3) sT[j * 12 + r * 4 + c] = transforms[i];
    }
    if (tid < NJ * 9)  sF[tid] = sh_feats[tid];
    if (tid < NJ * 3)  sL[tid] = locs[tid];
    __syncthreads();

    int n = blockIdx.x * 256 + tid;
    if (n >= N) return;

    const float x0 = xyz[3 * n + 0];
    const float x1 = xyz[3 * n + 1];
    const float x2 = xyz[3 * n + 2];
    const float v0 = vdirs[3 * n + 0];
    const float v1 = vdirs[3 * n + 1];
    const float v2 = vdirs[3 * n + 2];

    float wsum = 0.0f;
    float A[12];
#pragma unroll
    for (int k = 0; k < 12; ++k) A[k] = 0.0f;

#pragma unroll 4
    for (int j = 0; j < NJ; ++j) {
        const float* T = &sT[j * 12];
        // per-joint transform of the point
        float p0 = T[0] * x0 + T[1] * x1 + T[2]  * x2 + T[3];
        float p1 = T[4] * x0 + T[5] * x1 + T[6]  * x2 + T[7];
        float p2 = T[8] * x0 + T[9] * x1 + T[10] * x2 + T[11];
        float d0 = sL[j * 3 + 0] - p0;
        float d1 = sL[j * 3 + 1] - p1;
        float d2 = sL[j * 3 + 2] - p2;
        float len2 = d0 * d0 + d1 * d1 + d2 * d2;
        float rlen = rsqrtf(fmaxf(len2, 1e-30f));       // NaN insurance for len2==0
        float len  = len2 * rlen;                       // sqrt via rsqrt
        float dx = d0 * rlen, dy = d1 * rlen, dz = d2 * rlen;

        const float* F = &sF[j * 9];
        float dot = SH_C0 * F[0]
                  - SH_C1 * dy * F[1]
                  + SH_C1 * dz * F[2]
                  - SH_C1 * dx * F[3]
                  + C2_0 * (dx * dy) * F[4]
                  + C2_1 * (dy * dz) * F[5]
                  + C2_2 * (2.0f * dz * dz - dx * dx - dy * dy) * F[6]
                  + C2_3 * (dx * dz) * F[7]
                  + C2_4 * (dx * dx - dy * dy) * F[8];
        float rads = fmaxf(dot + 0.5f, 0.0f);
        float rel  = fmaxf(1.0f - __fdividef(len, fmaxf(rads, EPSF)), 0.0f);
        rel = (rads < EPSF) ? 0.0f : rel;

        wsum += rel;
#pragma unroll
        for (int k = 0; k < 12; ++k) A[k] += rel * T[k];
    }

    const float inv = __fdividef(1.0f, fmaxf(wsum, EPSF));
    float bx0 = (A[0] * x0 + A[1] * x1 + A[2]  * x2 + A[3])  * inv;
    float bx1 = (A[4] * x0 + A[5] * x1 + A[6]  * x2 + A[7])  * inv;
    float bx2 = (A[8] * x0 + A[9] * x1 + A[10] * x2 + A[11]) * inv;
    // translation cancels in xyz - (xyz - viewdirs): rotation-only on v
    float bv0 = (A[0] * v0 + A[1] * v1 + A[2]  * v2) * inv;
    float bv1 = (A[4] * v0 + A[5] * v1 + A[6]  * v2) * inv;
    float bv2 = (A[8] * v0 + A[9] * v1 + A[10] * v2) * inv;

    const bool valid = wsum > EPSF;
    float o0 = valid ? bx0 : x0;
    float o1 = valid ? bx1 : x1;
    float o2 = valid ? bx2 : x2;
    float w0 = valid ? bv0 : v0;
    float w1 = valid ? bv1 : v1;
    float w2 = valid ? bv2 : v2;

    out[3 * n + 0] = o0;
    out[3 * n + 1] = o1;
    out[3 * n + 2] = o2;
    float* outv = out + 3LL * N;
    outv[3 * n + 0] = w0;
    outv[3 * n + 1] = w1;
    outv[3 * n + 2] = w2;
}

extern "C" void kernel_launch(void* const* d_in, const int* in_sizes, int n_in,
                              void* d_out, int out_size, void* d_ws, size_t ws_size,
                              hipStream_t stream) {
    const float* xyz        = (const float*)d_in[0];
    const float* vdirs      = (const float*)d_in[1];
    const float* transforms = (const float*)d_in[2];
    const float* sh_feats   = (const float*)d_in[3];
    const float* locs       = (const float*)d_in[4];
    float* out = (float*)d_out;

    const int N = in_sizes[0] / 3;   // 2048*128 = 262144 points
    if (N <= 0) return;
    const int threads = 256;
    const int blocks = (N + threads - 1) / threads;
    shCaster_kernel<<<blocks, threads, 0, stream>>>(
        xyz, vdirs, transforms, sh_feats, locs, out, N);
}